// Round 9
// baseline (225.165 us; speedup 1.0000x reference)
//
#include <hip/hip_runtime.h>
#include <cstdint>
#include <cstddef>

// Problem constants (B=128, S=256, H=128, HEADS=8, STEP=1)
#define BB   128
#define SS   256
#define HH   128
#define NH   8
#define DKK  16

typedef unsigned short u16;
typedef __attribute__((ext_vector_type(8))) short   sh8;    // 8 bf16 = 4 VGPRs (MFMA A/B frag)
typedef __attribute__((ext_vector_type(4))) float   f32x4;  // MFMA C/D frag

__device__ __forceinline__ float sigmoidf_(float x) { return 1.f / (1.f + expf(-x)); }

__device__ __forceinline__ u16 f2bf(float x) {
    union { float f; unsigned int u; } v; v.f = x;
    unsigned int r = (v.u + 0x7fffu + ((v.u >> 16) & 1u)) >> 16;  // RNE (finite inputs)
    return (u16)r;
}
__device__ __forceinline__ float bf2f(u16 u) {
    union { unsigned int u; float f; } v; v.u = ((unsigned int)u) << 16;
    return v.f;
}
__device__ __forceinline__ float bflo(unsigned u) {
    union { unsigned u; float f; } v; v.u = u << 16; return v.f;
}
__device__ __forceinline__ float bfhi(unsigned u) {
    union { unsigned u; float f; } v; v.u = u & 0xffff0000u; return v.f;
}

// ---------------------------------------------------------------------------
// bf16 MFMA GEMM, 128x128 tile, BK=32, 256 threads = 4 waves, each wave 64x64
// (4x4 grid of 16x16x32 MFMA).  B operands are B^T layout [N][K] bf16.
// Software-pipelined via NAMED register variables and straight-line macro
// loads — NO lambdas/arrays (round-5: lambda capture -> alloca -> 156 MB
// scratch traffic, 45->74 us regression).
// XMODE: 0 = bf16 [M][K] row-major
//        1 = fp32 [M][K] (convert to bf16 while staging)
//        2 = concat along K: bf16 Xa (ld ldx) for k<ksplit, bf16 Xc (ld ldx1) after
// OMODE: 1 = bf16 row-major
//        2 = bf16 TRANSPOSED (Out[col*ldo + row], packed ushort4 per C-quad)
//        3 = fused GRU gate epilogue, LDS-gather (W2 cols gate-interleaved,
//            col=4c+g, g: 0=r 1=i 2=n 3=hn); hnew = h - sig(gi)*(h -
//            tanh(i_n + sig(gr)*h_n)); h read from bf16 hid; coalesced stores.
// Batch (grid.z): z -> zb=z>>1, zh=z&1; element offsets = zb*s?b + zh*s?h.
// All dims are exact multiples of tile sizes for every call — no bounds checks.
// ---------------------------------------------------------------------------
#define BKk 32
#define PK  40   // LDS K pitch in halves (32 + 8): conflict-free frag reads

template<int XMODE, int OMODE>
__global__ __launch_bounds__(256) void gemm_mfma(
    const void* __restrict__ Xa, const void* __restrict__ Xc, int ldx, int ldx1, int ksplit,
    long long sXb, long long sXh,
    const u16* __restrict__ Bw, int ldb, long long sBb, long long sBh,
    const float* __restrict__ bias,
    void* __restrict__ Out, long long ldo, long long sOb, long long sOh,
    int K, const u16* __restrict__ hid)
{
    __shared__ __align__(16) char smem[2 * 128 * PK * 2];  // 20480 B
    u16* As = (u16*)smem;
    u16* Bs = (u16*)(smem + 128 * PK * 2);

    const int t  = threadIdx.x;
    const int bm = blockIdx.x * 128;
    const int bn = blockIdx.y * 128;
    const long long zb = blockIdx.z >> 1, zh = blockIdx.z & 1;

    const u16* Bp = Bw + zb * sBb + zh * sBh;

    const int wave = t >> 6, lane = t & 63;
    const int wr = (wave >> 1) * 64, wc = (wave & 1) * 64;
    const int fm = lane & 15, fq = lane >> 4;

    f32x4 acc[4][4] = {};

    const int r0  = t >> 2, kk0 = (t & 3) * 8;  // bf16 staging: 8 halves (16B), 2 chunks
    const int r1  = t >> 3, kk1 = (t & 7) * 4;  // fp32 staging: 4 floats, 4 chunks

    // prefetch registers — named scalars only (keep them out of scratch!)
    uint4  px0, px1, pb0, pb1;
    float4 pf0, pf1, pf2, pf3;

#define LOADX(K0)                                                                    \
    if (XMODE == 1) {                                                                \
        const float* Xf_ = (const float*)Xa + zb * sXb + zh * sXh;                   \
        const float* xp_ = Xf_ + (long long)(bm + r1) * ldx + (K0) + kk1;            \
        pf0 = *(const float4*)(xp_);                                                 \
        pf1 = *(const float4*)(xp_ + 32LL * ldx);                                    \
        pf2 = *(const float4*)(xp_ + 64LL * ldx);                                    \
        pf3 = *(const float4*)(xp_ + 96LL * ldx);                                    \
    } else if (XMODE == 2 && (K0) >= ksplit) {                                       \
        const u16* xp_ = (const u16*)Xc + (long long)(bm + r0) * ldx1                \
                         + ((K0) - ksplit) + kk0;                                    \
        px0 = *(const uint4*)(xp_);                                                  \
        px1 = *(const uint4*)(xp_ + 64LL * ldx1);                                    \
    } else {                                                                         \
        const u16* xp_ = (const u16*)Xa + (long long)(bm + r0) * ldx + (K0) + kk0;   \
        px0 = *(const uint4*)(xp_);                                                  \
        px1 = *(const uint4*)(xp_ + 64LL * ldx);                                     \
    }

#define LOADB(K0)                                                                    \
    {                                                                                \
        const u16* bp_ = Bp + (long long)(bn + r0) * ldb + (K0) + kk0;               \
        pb0 = *(const uint4*)(bp_);                                                  \
        pb1 = *(const uint4*)(bp_ + 64LL * ldb);                                     \
    }

    LOADX(0)
    LOADB(0)

    for (int k0 = 0; k0 < K; k0 += BKk) {
        // ---- commit prefetched tile to LDS ----
        if (XMODE == 1) {
            ushort4 w0 = { f2bf(pf0.x), f2bf(pf0.y), f2bf(pf0.z), f2bf(pf0.w) };
            ushort4 w1 = { f2bf(pf1.x), f2bf(pf1.y), f2bf(pf1.z), f2bf(pf1.w) };
            ushort4 w2 = { f2bf(pf2.x), f2bf(pf2.y), f2bf(pf2.z), f2bf(pf2.w) };
            ushort4 w3 = { f2bf(pf3.x), f2bf(pf3.y), f2bf(pf3.z), f2bf(pf3.w) };
            *(ushort4*)&As[(r1     ) * PK + kk1] = w0;
            *(ushort4*)&As[(r1 + 32) * PK + kk1] = w1;
            *(ushort4*)&As[(r1 + 64) * PK + kk1] = w2;
            *(ushort4*)&As[(r1 + 96) * PK + kk1] = w3;
        } else {
            *(uint4*)&As[(r0     ) * PK + kk0] = px0;
            *(uint4*)&As[(r0 + 64) * PK + kk0] = px1;
        }
        *(uint4*)&Bs[(r0     ) * PK + kk0] = pb0;
        *(uint4*)&Bs[(r0 + 64) * PK + kk0] = pb1;
        __syncthreads();

        // ---- issue next-tile loads (hide HBM latency behind frag+MFMA) ----
        if (k0 + BKk < K) {
            LOADX(k0 + BKk)
            LOADB(k0 + BKk)
        }

        sh8 af[4], bfr[4];
        #pragma unroll
        for (int i = 0; i < 4; i++) af[i]  = *(const sh8*)&As[(wr + i * 16 + fm) * PK + fq * 8];
        #pragma unroll
        for (int j = 0; j < 4; j++) bfr[j] = *(const sh8*)&Bs[(wc + j * 16 + fm) * PK + fq * 8];
        #pragma unroll
        for (int i = 0; i < 4; i++)
            #pragma unroll
            for (int j = 0; j < 4; j++)
                acc[i][j] = __builtin_amdgcn_mfma_f32_16x16x32_bf16(af[i], bfr[j], acc[i][j], 0, 0, 0);
        __syncthreads();
    }
#undef LOADX
#undef LOADB

    if (OMODE != 3) {
        // ---- epilogue: C layout col=lane&15, row=(lane>>4)*4+reg ----
        #pragma unroll
        for (int j = 0; j < 4; j++) {
            const int col = bn + wc + j * 16 + fm;
            const float bj = bias ? bias[col] : 0.f;
            #pragma unroll
            for (int i = 0; i < 4; i++) {
                const int row0 = bm + wr + i * 16 + fq * 4;
                if (OMODE == 1) {
                    u16* O = (u16*)Out + zb * sOb + zh * sOh;
                    #pragma unroll
                    for (int r = 0; r < 4; r++)
                        O[(long long)(row0 + r) * ldo + col] = f2bf(acc[i][j][r] + bj);
                } else {  // OMODE == 2
                    u16* O = (u16*)Out + zb * sOb + zh * sOh;
                    ushort4 w = { f2bf(acc[i][j][0] + bj), f2bf(acc[i][j][1] + bj),
                                  f2bf(acc[i][j][2] + bj), f2bf(acc[i][j][3] + bj) };
                    *(ushort4*)&O[(long long)col * ldo + row0] = w;  // 4 consecutive rows
                }
            }
        }
    } else {
        // ---- OMODE == 3: fused GRU epilogue, LDS-gather ----
        float* g4s = (float*)smem;       // [32][132] fp32 = 16896 B (reuses As/Bs)
        const int chbase = bn >> 2;      // global channel base for this block
        const int s_t = t >> 3;          // 0..31 slab row
        const int cq  = t & 7;           // 0..7 channel quad
        u16* O = (u16*)Out;
        const int sbase = (wr ? 16 : 0) + fq * 4;
        #pragma unroll
        for (int i = 0; i < 4; i++) {
            // scatter acc+bias into LDS (rows of both wave halves -> 32 slab rows)
            #pragma unroll
            for (int j = 0; j < 4; j++) {
                const int q = wc + j * 16 + fm;
                const float bj = bias[bn + q];
                #pragma unroll
                for (int r = 0; r < 4; r++)
                    g4s[(sbase + r) * 132 + q] = acc[i][j][r] + bj;
            }
            __syncthreads();
            // gather: 1 row x 4 channels per thread, contiguous b128 reads
            {
                const int grow = bm + i * 16 + (s_t < 16 ? s_t : s_t + 48);
                const ushort4 hv = *(const ushort4*)&hid[(long long)grow * HH + chbase + 4 * cq];
                const float hvv[4] = { bf2f(hv.x), bf2f(hv.y), bf2f(hv.z), bf2f(hv.w) };
                ushort4 w;
                u16* wp = (u16*)&w;
                #pragma unroll
                for (int m = 0; m < 4; m++) {
                    f32x4 gv = *(const f32x4*)&g4s[s_t * 132 + 16 * cq + 4 * m];
                    float rg = sigmoidf_(gv[0]);
                    float ig = sigmoidf_(gv[1]);
                    float ng = tanhf(gv[2] + rg * gv[3]);
                    wp[m] = f2bf(hvv[m] - ig * (hvv[m] - ng));
                }
                *(ushort4*)&O[(long long)grow * ldo + chbase + 4 * cq] = w;
            }
            __syncthreads();
        }
    }
}

// ---------------------------------------------------------------------------
// Weight prep + hidden cast (grid 4096x256).
//   h_bf = bf16(hidden)  (1048576 float4s)
//   W2bf [512x384], GATE-INTERLEAVED rows: np = 4c+g, g: 0=r 1=i 2=n 3=hn.
//   bias2[np] = gate bias + fold of (b_iah|b_oah) through w_ih (linear terms).
//   Wcat [256x128] = [W_ein; W_eout], biascat = [b_ein|b_eout]
// (q12 weights no longer staged — the attention tail consumes hnew directly.)
// ---------------------------------------------------------------------------
__global__ __launch_bounds__(256) void k_prepw(
    const float* __restrict__ hidden, u16* __restrict__ h_bf,
    const float* __restrict__ w_ih, const float* __restrict__ w_hh,
    const float* __restrict__ b_ih, const float* __restrict__ b_hh,
    const float* __restrict__ b_iah, const float* __restrict__ b_oah,
    const float* __restrict__ W_ein, const float* __restrict__ b_ein,
    const float* __restrict__ W_eout, const float* __restrict__ b_eout,
    u16* __restrict__ W2bf, float* __restrict__ bias2,
    u16* __restrict__ Wcat, float* __restrict__ biascat)
{
    int idx = blockIdx.x * 256 + threadIdx.x;  // 0 .. 1048575
    {   // hidden -> bf16, 4 elems/thread
        float4 v = ((const float4*)hidden)[idx];
        ushort4 w = { f2bf(v.x), f2bf(v.y), f2bf(v.z), f2bf(v.w) };
        ((ushort4*)h_bf)[idx] = w;
    }
    if (idx < 512 * 384) {
        int np = idx / 384, kk = idx % 384;
        int c = np >> 2, g = np & 3;
        float v;
        if (g < 2)       v = (kk < 256) ? w_ih[(g * 128 + c) * 256 + kk]
                                        : w_hh[(g * 128 + c) * 128 + kk - 256];
        else if (g == 2) v = (kk < 256) ? w_ih[(256 + c) * 256 + kk] : 0.f;
        else             v = (kk < 256) ? 0.f : w_hh[(256 + c) * 128 + kk - 256];
        W2bf[idx] = f2bf(v);
    }
    if (idx < 256 * 128) {
        int n = idx >> 7, k = idx & 127;
        Wcat[idx] = f2bf(n < 128 ? W_ein[n * 128 + k] : W_eout[(n - 128) * 128 + k]);
    }
    if (idx < 512) {
        int np = idx, c = np >> 2, g = np & 3;
        float s;
        if (g < 2)       s = b_ih[g * 128 + c] + b_hh[g * 128 + c];
        else if (g == 2) s = b_ih[256 + c];
        else             s = b_hh[256 + c];
        if (g < 3) {
            int n = (g < 2) ? g * 128 + c : 256 + c;
            for (int k = 0; k < 128; k++)
                s += w_ih[n * 256 + k] * b_iah[k] + w_ih[n * 256 + 128 + k] * b_oah[k];
        }
        bias2[np] = s;
    }
    if (idx < 256) {
        biascat[idx] = idx < 128 ? b_ein[idx] : b_eout[idx - 128];
    }
}

// ---------------------------------------------------------------------------
// Fused attention tail v3: one block per batch b, 1024 threads. The q1/q2
// projections are folded in algebraically (q12 GEMM eliminated):
//   scores: s[h,j] = q0t[h]·hnew[j] + cb[h],  q0t[h] = q0[h]@Wq1[16h:16h+16]
//   readout: out[col] = nv·( y[h(col)]·Wq2[col] + bq2[col]·sw[h] ),
//            y[h,c] = Σ_j w[h,j]·hnew[j,c],  sw[h] = Σ_j w[h,j].
// hnew[b] (64 KB) staged in LDS row-major: conflict-free for the y column
// loop (lanes read consecutive c at fixed j); scores read rows from GLOBAL
// (L2-served) to avoid the row-stride LDS bank conflict.
// ---------------------------------------------------------------------------
__global__ __launch_bounds__(1024) void k_tail(
    const u16* __restrict__ hnew_bf, const int* __restrict__ mask,
    const float* __restrict__ Wq0, const float* __restrict__ bq0,
    const float* __restrict__ Wq1, const float* __restrict__ bq1,
    const float* __restrict__ Wq2, const float* __restrict__ bq2,
    float* __restrict__ out)
{
    const int b = blockIdx.x, t = threadIdx.x;
    __shared__ u16   hL[SS * HH];      // 65536 B, row-major [j][c]
    __shared__ float red[1024];
    __shared__ float q0s[HH];
    __shared__ float q0t[NH][HH];
    __shared__ float cbs[NH];
    __shared__ float p_s[NH][SS];
    __shared__ float w_s[NH][SS];
    __shared__ float ybuf[NH][HH];
    __shared__ float swb[NH];
    __shared__ int s_nv;

    const u16* hrow = hnew_bf + (size_t)b * SS * HH;

    // ---- stage hnew[b] into LDS (coalesced uint4, 4 per thread) ----
    {
        const uint4* src = (const uint4*)hrow;
        uint4* dst = (uint4*)hL;
        #pragma unroll
        for (int i = 0; i < 4; i++) dst[t + 1024 * i] = src[t + 1024 * i];
    }
    // ---- mask sum / last index ----
    if (t < 256) red[t] = (float)mask[b * SS + t];
    __syncthreads();  // also covers hL staging
    for (int off = 128; off > 0; off >>= 1) {
        if (t < off) red[t] += red[t + off];
        __syncthreads();
    }
    if (t == 0) s_nv = (int)red[0];
    __syncthreads();
    const int nv = s_nv;
    const int last = (nv - 1) & (SS - 1);

    // ---- q0 = hnew[last] @ Wq0^T + bq0: n = t&127, K split 8 ways ----
    {
        const int n = t & 127, kh = t >> 7;
        const float* w = Wq0 + (size_t)n * HH + kh * 16;
        const u16* h = hL + last * HH + kh * 16;
        float s = 0.f;
        #pragma unroll
        for (int k = 0; k < 16; k++) s += bf2f(h[k]) * w[k];
        red[t] = s;
    }
    __syncthreads();
    if (t < HH) {
        float s = bq0[t];
        #pragma unroll
        for (int kh = 0; kh < 8; kh++) s += red[kh * 128 + t];
        q0s[t] = s;
    }
    __syncthreads();

    // ---- q0t[h][c] = sum_d q0s[16h+d] * Wq1[(16h+d)*128 + c] ----
    {
        const int h = t >> 7, c = t & 127;
        const float* w = Wq1 + (size_t)(h * 16) * HH + c;
        float s = 0.f;
        #pragma unroll
        for (int d = 0; d < 16; d++) s += q0s[h * 16 + d] * w[(size_t)d * HH];
        q0t[h][c] = s;
    }
    if (t < NH) {
        float s = 0.f;
        #pragma unroll
        for (int d = 0; d < 16; d++) s += q0s[t * 16 + d] * bq1[t * 16 + d];
        cbs[t] = s;
    }
    __syncthreads();

    // ---- scores: j = t&255, hp = t>>8 -> heads 2hp, 2hp+1 (rows from L2) ----
    {
        const int j = t & 255, hp = t >> 8;
        const u16* hr = hrow + (size_t)j * HH;
        const float* qa = &q0t[2 * hp][0];
        const float* qb = &q0t[2 * hp + 1][0];
        float s0 = 0.f, s1 = 0.f;
        #pragma unroll 4
        for (int c8 = 0; c8 < 16; c8++) {
            uint4 v = *(const uint4*)(hr + c8 * 8);
            const int c0 = c8 * 8;
            float x0 = bflo(v.x), x1 = bfhi(v.x), x2 = bflo(v.y), x3 = bfhi(v.y);
            float x4 = bflo(v.z), x5 = bfhi(v.z), x6 = bflo(v.w), x7 = bfhi(v.w);
            s0 += qa[c0] * x0 + qa[c0 + 1] * x1 + qa[c0 + 2] * x2 + qa[c0 + 3] * x3
                + qa[c0 + 4] * x4 + qa[c0 + 5] * x5 + qa[c0 + 6] * x6 + qa[c0 + 7] * x7;
            s1 += qb[c0] * x0 + qb[c0 + 1] * x1 + qb[c0 + 2] * x2 + qb[c0 + 3] * x3
                + qb[c0 + 4] * x4 + qb[c0 + 5] * x5 + qb[c0 + 6] * x6 + qb[c0 + 7] * x7;
        }
        p_s[2 * hp][j]     = sigmoidf_(s0 + cbs[2 * hp]);
        p_s[2 * hp + 1][j] = sigmoidf_(s1 + cbs[2 * hp + 1]);
    }
    __syncthreads();

    // ---- softmax over j per head (threads 0..255: 32 lanes/head, 8 vals) ----
    if (t < 256) {
        const int h = t >> 5, l = t & 31;
        float v[8], m = -1e30f;
        #pragma unroll
        for (int u = 0; u < 8; u++) { v[u] = p_s[h][l * 8 + u]; m = fmaxf(m, v[u]); }
        #pragma unroll
        for (int msk = 1; msk < 32; msk <<= 1) m = fmaxf(m, __shfl_xor(m, msk, 32));
        float sum = 0.f;
        #pragma unroll
        for (int u = 0; u < 8; u++) { v[u] = expf(v[u] - m); sum += v[u]; }
        #pragma unroll
        for (int msk = 1; msk < 32; msk <<= 1) sum += __shfl_xor(sum, msk, 32);
        const float inv = 1.f / sum;
        #pragma unroll
        for (int u = 0; u < 8; u++) p_s[h][l * 8 + u] = v[u] * inv;
    }
    __syncthreads();

    // ---- head softmax per j (threads 0..255) -> w_s ----
    if (t < 256) {
        float e[NH], den = 0.f;
        #pragma unroll
        for (int h = 0; h < NH; h++) { e[h] = expf(2.f * p_s[h][t]); den += e[h]; }
        const float inv = 1.f / den;
        #pragma unroll
        for (int h = 0; h < NH; h++) w_s[h][t] = e[h] * inv;
    }
    __syncthreads();

    // ---- sw[h] = sum_j w_s[h][j] (threads 0..255, shuffle reduce) ----
    if (t < 256) {
        const int h = t >> 5, l = t & 31;
        float s = 0.f;
        #pragma unroll
        for (int u = 0; u < 8; u++) s += w_s[h][l * 8 + u];
        #pragma unroll
        for (int msk = 1; msk < 32; msk <<= 1) s += __shfl_xor(s, msk, 32);
        if (l == 0) swb[h] = s;
    }

    // ---- y[h][c] = sum_j w_s[h][j] * hnew[j][c]  (LDS, conflict-free) ----
    {
        const int h = t >> 7, c = t & 127;
        float s = 0.f;
        #pragma unroll 8
        for (int j = 0; j < 256; j++) s += w_s[h][j] * bf2f(hL[j * HH + c]);
        ybuf[h][c] = s;
    }
    __syncthreads();

    // ---- out[col] = nv * ( y[h]·Wq2[col] + bq2[col]*sw[h] ) ----
    if (t < HH) {
        const int col = t, h = col >> 4;
        const float* w = Wq2 + (size_t)col * HH;
        float s = 0.f;
        #pragma unroll 8
        for (int c = 0; c < 128; c++) s += ybuf[h][c] * w[c];
        out[(size_t)b * HH + col] = (s + bq2[col] * swb[h]) * (float)nv;
    }
}

// ---------------------------------------------------------------------------
extern "C" void kernel_launch(void* const* d_in, const int* in_sizes, int n_in,
                              void* d_out, int out_size, void* d_ws, size_t ws_size,
                              hipStream_t stream)
{
    const float* A      = (const float*)d_in[0];
    const float* hidden = (const float*)d_in[1];
    const int*   mask   = (const int*)d_in[2];
    const float* w_ih   = (const float*)d_in[3];
    const float* w_hh   = (const float*)d_in[4];
    const float* b_ih   = (const float*)d_in[5];
    const float* b_hh   = (const float*)d_in[6];
    const float* b_iah  = (const float*)d_in[7];
    const float* b_oah  = (const float*)d_in[8];
    const float* W_ein  = (const float*)d_in[9];
    const float* b_ein  = (const float*)d_in[10];
    const float* W_eout = (const float*)d_in[11];
    const float* b_eout = (const float*)d_in[12];
    const float* W_q0   = (const float*)d_in[13];
    const float* b_q0   = (const float*)d_in[14];
    const float* W_q1   = (const float*)d_in[15];
    const float* b_q1   = (const float*)d_in[16];
    const float* W_q2   = (const float*)d_in[17];
    const float* b_q2   = (const float*)d_in[18];
    float* out = (float*)d_out;
    char* ws = (char*)d_ws;

    // --- workspace layout (bytes) ---
    u16*   Et      = (u16*)(ws + 0);             // [256][32768] bf16 (E transposed)
    u16*   Mbuf    = (u16*)(ws + 16777216);      // [32768][256] bf16 (msg_in|msg_out)
    u16*   hnew_bf = (u16*)(ws + 33554432);      // [32768][128] bf16
    u16*   h_bf    = (u16*)(ws + 41943040);      // [32768][128] bf16
    u16*   W2bf    = (u16*)(ws + 50331648);      // [512][384]
    u16*   Wcat    = (u16*)(ws + 50724864);      // [256][128]
    float* bias2   = (float*)(ws + 50790400);    // [512]
    float* biascat = (float*)(ws + 50792448);    // [256]

    // 1. weight prep + hidden cast
    k_prepw<<<4096, 256, 0, stream>>>(hidden, h_bf,
                                      w_ih, w_hh, b_ih, b_hh, b_iah, b_oah,
                                      W_ein, b_ein, W_eout, b_eout,
                                      W2bf, bias2, Wcat, biascat);

    // 2. E = h_bf @ [W_ein;W_eout]^T + bias, stored TRANSPOSED (Et[c][r])
    gemm_mfma<0, 2><<<dim3(256, 2, 1), 256, 0, stream>>>(
        h_bf, nullptr, HH, 0, 0, 0, 0,
        Wcat, HH, 0, 0, biascat,
        Et, 32768, 0, 0, HH, nullptr);

    // 3. msg: per (b,half): A-half[b] (fp32, ld 512) @ Et-slice^T -> Mbuf bf16
    gemm_mfma<1, 1><<<dim3(2, 1, 256), 256, 0, stream>>>(
        A, nullptr, 512, 0, 0, 131072LL, 256LL,
        Et, 32768, 256LL, 128LL * 32768LL, nullptr,
        Mbuf, 256, 65536LL, 128LL, SS, nullptr);

    // 4. gates = [Mbuf | h_bf] @ W2bf^T + bias2, fused GRU epilogue
    //    (LDS-gather) -> hnew bf16 directly
    gemm_mfma<2, 3><<<dim3(256, 4, 1), 256, 0, stream>>>(
        Mbuf, h_bf, 256, HH, 256, 0, 0,
        W2bf, 384, 0, 0, bias2,
        hnew_bf, HH, 0, 0, 384, h_bf);

    // 5. fused attention tail v3 (q12 GEMM folded in; 1024 threads/block)
    k_tail<<<BB, 1024, 0, stream>>>(hnew_bf, mask,
                                    W_q0, b_q0, W_q1, b_q1, W_q2, b_q2, out);
}